// Round 1
// baseline (347.213 us; speedup 1.0000x reference)
//
#include <hip/hip_runtime.h>

// StreamNet K3 S1 halo conv: B=8, C=32, P=256, KB=2, R_MASK=1
// Padded input Xp[b][c][r][cc], r,cc in [0,258):
//   r < 2           -> bbuf[b][c][r][cc]           (bbuf is [B][C][2][258])
//   r>=2, cc < 2    -> rbuf[b][c][r-2][cc]         (rbuf is [B][C][256][2])
//   r>=2, cc>=2     -> (cc-2 == 255) ? 0 : x[b][c][r-2][cc-2]
// out[b][oc][y][x] = bias[oc] + sum_{ic,ky,kx} W[oc][ic][ky][kx] * Xp[b][ic][y+ky][x+kx]

constexpr int B  = 8;
constexpr int C  = 32;
constexpr int P  = 256;
constexpr int KB = 2;
constexpr int TILE = 16;              // 16x16 output tile per block
constexpr int HT = TILE + KB;         // 18 halo tile side
constexpr int LDS_STRIDE = 24;        // pad 18 -> 24: 2-way bank aliasing only (free)

__global__ __launch_bounds__(256) void streamnet_conv_kernel(
    const float* __restrict__ x,      // [B][C][P][P]
    const float* __restrict__ rbuf,   // [B][C][P][KB]
    const float* __restrict__ bbuf,   // [B][C][KB][P+KB]
    const float* __restrict__ W,      // [C][C][3][3]
    const float* __restrict__ bias,   // [C]
    float* __restrict__ out)          // [B][C][P][P]
{
    const int blk = blockIdx.x;            // b*256 + ty*16 + tx
    const int tx  = blk & 15;
    const int ty  = (blk >> 4) & 15;
    const int b   = blk >> 8;

    const int tid = threadIdx.x;
    const int lx  = tid & 15;              // output col within tile
    const int ly  = tid >> 4;              // output row within tile

    const int y0 = ty * TILE;              // output (== Xp top-left) row base
    const int x0 = tx * TILE;

    __shared__ float s[HT * LDS_STRIDE];

    float acc[C];
    #pragma unroll
    for (int oc = 0; oc < C; ++oc) acc[oc] = bias[oc];

    for (int ic = 0; ic < C; ++ic) {
        __syncthreads();   // previous iteration's reads of s[] are done

        // ---- stage 18x18 Xp patch into LDS, resolving halo sources ----
        const float* xb = x    + ((size_t)(b * C + ic) * P) * P;
        const float* rb = rbuf + ((size_t)(b * C + ic) * P) * KB;
        const float* bb = bbuf + ((size_t)(b * C + ic) * KB) * (P + KB);

        for (int idx = tid; idx < HT * HT; idx += 256) {
            const int rr = idx / HT;       // row within patch
            const int cc = idx % HT;       // col within patch
            const int r  = y0 + rr;        // Xp row
            const int c  = x0 + cc;        // Xp col
            float v;
            if (r < KB) {
                v = bb[r * (P + KB) + c];
            } else {
                const int xr = r - KB;
                if (c < KB) {
                    v = rb[xr * KB + c];
                } else {
                    const int xc = c - KB;
                    v = (xc == P - 1) ? 0.0f : xb[xr * P + xc];
                }
            }
            s[rr * LDS_STRIDE + cc] = v;
        }
        __syncthreads();

        // ---- gather 3x3 receptive field into registers ----
        float in[9];
        #pragma unroll
        for (int ky = 0; ky < 3; ++ky)
            #pragma unroll
            for (int kx = 0; kx < 3; ++kx)
                in[ky * 3 + kx] = s[(ly + ky) * LDS_STRIDE + lx + kx];

        // ---- 32 oc x 9 taps; W indices are block-uniform -> scalar loads ----
        #pragma unroll
        for (int oc = 0; oc < C; ++oc) {
            const float* w = W + ((size_t)(oc * C + ic) * 9);
            #pragma unroll
            for (int k = 0; k < 9; ++k)
                acc[oc] = fmaf(w[k], in[k], acc[oc]);
        }
    }

    // ---- epilogue: coalesced-by-16 stores ----
    const int y  = y0 + ly;
    const int xx = x0 + lx;
    #pragma unroll
    for (int oc = 0; oc < C; ++oc)
        out[((size_t)(b * C + oc) * P + y) * P + xx] = acc[oc];
}

extern "C" void kernel_launch(void* const* d_in, const int* in_sizes, int n_in,
                              void* d_out, int out_size, void* d_ws, size_t ws_size,
                              hipStream_t stream) {
    const float* x    = (const float*)d_in[0];
    const float* rbuf = (const float*)d_in[1];
    const float* bbuf = (const float*)d_in[2];
    const float* W    = (const float*)d_in[3];
    const float* bias = (const float*)d_in[4];
    float* out = (float*)d_out;

    const int grid = B * (P / TILE) * (P / TILE);   // 8 * 16 * 16 = 2048
    streamnet_conv_kernel<<<grid, 256, 0, stream>>>(x, rbuf, bbuf, W, bias, out);
}